// Round 16
// baseline (36.267 us; speedup 1.0000x reference)
//
#include <hip/hip_runtime.h>

// MinibatchDiscrimination, round 16 — pair phase at 4 waves/SIMD:
//   K1 kA    : xpT[s][kd][i] = partial (inputs @ T)^T  (unchanged, ~7us warm)
//   K2 kB    : xT[kd][i] = log2e * sum_s xpT[s][kd][i]  (coalesced, ~1.5us)
//   K3 pairW : out[i,k] = sum_j exp2(-L1).  200 blocks x 1024 thr (16 waves,
//              4/SIMD), wave w: j in [32w,32w+32), R=4 i-rows/lane, 16-way
//              LDS reduce, direct writes.
//
// inputs [512,1024] f32, T [1024,500] f32, out [512,100] f32.

#define BB 512
#define FF 1024
#define KK 100
#define KD 500
#define KDP 512
#define SPLITS 8
#define FN (FF / SPLITS)   // 128 f per split
#define STEPS (FN / 16)    // 8
#define LOG2E 1.4426950408889634f

// ---------------- K1: split-K GEMM tile, transposed partial store ---------
// grid = 512 blocks (8 i x 8 kd x 8 splits), block 256, 2/CU.
__global__ __launch_bounds__(256, 2) void kA(
    const float* __restrict__ in, const float* __restrict__ T,
    float* __restrict__ xpT)
{
    __shared__ __align__(16) float smem[2112];
    float (*Ads)[68] = (float(*)[68])smem;            // [16][68]
    float (*Bds)[64] = (float(*)[64])(smem + 1088);   // [16][64]

    const int b = blockIdx.x;
    const int t = threadIdx.x;
    const int i0  = (b & 7) * 64;
    const int kd0 = ((b >> 3) & 7) * 64;
    const int s   = b >> 6;                // 0..7
    const int tk  = t & 15;
    const int ti  = t >> 4;

    float acc[4][4];
    #pragma unroll
    for (int r = 0; r < 4; ++r)
        #pragma unroll
        for (int c = 0; c < 4; ++c) acc[r][c] = 0.f;

    const int ia  = t >> 2;                // i row for A staging
    const int fqa = t & 3;                 // f-quad for A
    const int kb  = t & 63;                // kd lane for B
    const int frb = t >> 6;                // f-quad for B
    const int kbc = min(kd0 + kb, KD - 1);

    const float* inb = in + (size_t)(i0 + ia) * FF + s * FN;
    const float* Tb  = T + (size_t)(s * FN) * KD + kbc;

    float4 av = *(const float4*)&inb[fqa * 4];
    float bv0 = Tb[(size_t)(frb * 4 + 0) * KD];
    float bv1 = Tb[(size_t)(frb * 4 + 1) * KD];
    float bv2 = Tb[(size_t)(frb * 4 + 2) * KD];
    float bv3 = Tb[(size_t)(frb * 4 + 3) * KD];

    for (int step = 0; step < STEPS; ++step) {
        Ads[fqa * 4 + 0][ia] = av.x;
        Ads[fqa * 4 + 1][ia] = av.y;
        Ads[fqa * 4 + 2][ia] = av.z;
        Ads[fqa * 4 + 3][ia] = av.w;
        Bds[frb * 4 + 0][kb] = bv0;
        Bds[frb * 4 + 1][kb] = bv1;
        Bds[frb * 4 + 2][kb] = bv2;
        Bds[frb * 4 + 3][kb] = bv3;
        __syncthreads();

        if (step + 1 < STEPS) {            // prefetch next step under the FMAs
            const int fo = (step + 1) * 16;
            av  = *(const float4*)&inb[fo + fqa * 4];
            bv0 = Tb[(size_t)(fo + frb * 4 + 0) * KD];
            bv1 = Tb[(size_t)(fo + frb * 4 + 1) * KD];
            bv2 = Tb[(size_t)(fo + frb * 4 + 2) * KD];
            bv3 = Tb[(size_t)(fo + frb * 4 + 3) * KD];
        }

        #pragma unroll
        for (int f = 0; f < 16; ++f) {
            float4 a  = *(const float4*)&Ads[f][ti * 4];
            float4 bq = *(const float4*)&Bds[f][tk * 4];
            float ar[4] = {a.x, a.y, a.z, a.w};
            float br[4] = {bq.x, bq.y, bq.z, bq.w};
            #pragma unroll
            for (int r = 0; r < 4; ++r)
                #pragma unroll
                for (int c = 0; c < 4; ++c)
                    acc[r][c] = fmaf(ar[r], br[c], acc[r][c]);
        }
        __syncthreads();
    }

    #pragma unroll
    for (int c = 0; c < 4; ++c) {
        float4 v = {acc[0][c], acc[1][c], acc[2][c], acc[3][c]};
        *(float4*)&xpT[((size_t)s * KDP + kd0 + tk * 4 + c) * BB + i0 + ti * 4] = v;
    }
}

// ---------------- K2: fold splits + scale, fully coalesced ---------------
// grid 256, block 256, one float4 per thread.
__global__ __launch_bounds__(256) void kB(
    const float* __restrict__ xpT, float* __restrict__ xT)
{
    const int e = blockIdx.x * 256 + threadIdx.x;    // float4 idx < 65536
    const float4* p = (const float4*)xpT;
    float4 v = p[e];
    #pragma unroll
    for (int s = 1; s < SPLITS; ++s) {
        float4 w = p[(size_t)s * (KDP * BB / 4) + e];
        v.x += w.x; v.y += w.y; v.z += w.z; v.w += w.w;
    }
    v.x *= LOG2E; v.y *= LOG2E; v.z *= LOG2E; v.w *= LOG2E;
    ((float4*)xT)[e] = v;
}

// ---------------- K3: pairwise exp2(-L1), 16 waves / 4 per SIMD -----------
// grid (100 k, 2 i-halves) = 200 blocks, block 1024.
// Wave w (0..15): j in [32w, 32w+32). Lane: i = ip*256 + r*64 + lane, r=0..3.
__global__ __launch_bounds__(1024) void pairW(
    const float* __restrict__ xT, float* __restrict__ out)
{
    const int k  = blockIdx.x;
    const int ip = blockIdx.y;
    const int t  = threadIdx.x;
    const int lane = t & 63;
    const int w    = t >> 6;          // 0..15

    __shared__ float xs[BB][8];       // 16 KiB
    __shared__ float ps[16][256];     // 16 KiB

    // fill 512 rows x 5 floats with 1024 threads (coalesced per-d segments)
    for (int e = t; e < BB * 5; e += 1024) {
        const int d = e >> 9;         // e / 512
        const int j = e & 511;
        xs[j][d] = xT[(size_t)(k * 5 + d) * BB + j];
    }
    __syncthreads();

    // register-resident xi: 4 i-rows per lane
    float xi[4][5];
    #pragma unroll
    for (int r = 0; r < 4; ++r) {
        const int i = ip * 256 + r * 64 + lane;
        float4 v = *(const float4*)&xs[i][0];
        xi[r][0] = v.x; xi[r][1] = v.y; xi[r][2] = v.z; xi[r][3] = v.w;
        xi[r][4] = xs[i][4];
    }

    float acc[4] = {0.f, 0.f, 0.f, 0.f};
    const int j0 = w << 5;            // 32 j per wave
    #pragma unroll 2
    for (int jj = 0; jj < 32; ++jj) {
        const int j = j0 + jj;        // wave-uniform -> LDS broadcast
        float4 xj = *(const float4*)&xs[j][0];
        float  x4 = xs[j][4];
        #pragma unroll
        for (int r = 0; r < 4; ++r) {
            float aa = (fabsf(xi[r][0] - xj.x) + fabsf(xi[r][1] - xj.y))
                     + (fabsf(xi[r][2] - xj.z) + fabsf(xi[r][3] - xj.w))
                     + fabsf(xi[r][4] - x4);
            acc[r] += __builtin_amdgcn_exp2f(-aa);
        }
    }

    #pragma unroll
    for (int r = 0; r < 4; ++r) ps[w][r * 64 + lane] = acc[r];
    __syncthreads();

    // reduce 16 wave-partials; threads 0..255 each own one i-row
    if (t < 256) {
        float v = 0.f;
        #pragma unroll
        for (int q = 0; q < 16; ++q) v += ps[q][t];
        out[(size_t)(ip * 256 + t) * KK + k] = v;
    }
}

// ---------------- last-resort fallback (ws too small) ----------------
__global__ __launch_bounds__(1024, 1) void mbd_fused(
    const float* __restrict__ in, const float* __restrict__ T, float* __restrict__ out)
{
    const int k = blockIdx.x;
    const int t = threadIdx.x;
    const int i = t & (BB - 1);
    const int h = t >> 9;

    __shared__ float xk[1024][8];

    float a0 = 0.f, a1 = 0.f, a2 = 0.f, a3 = 0.f, a4 = 0.f;
    const float4* inrow = (const float4*)(in + (size_t)i * FF + (size_t)h * 512);
    const float* Tk = T + 5 * k + (size_t)h * 512 * KD;

    for (int ff = 0; ff < 512; ff += 4) {
        float4 v = inrow[ff >> 2];
        const float* tp = Tk + (size_t)ff * KD;
        a0 = fmaf(v.x, tp[0], a0); a1 = fmaf(v.x, tp[1], a1); a2 = fmaf(v.x, tp[2], a2);
        a3 = fmaf(v.x, tp[3], a3); a4 = fmaf(v.x, tp[4], a4); tp += KD;
        a0 = fmaf(v.y, tp[0], a0); a1 = fmaf(v.y, tp[1], a1); a2 = fmaf(v.y, tp[2], a2);
        a3 = fmaf(v.y, tp[3], a3); a4 = fmaf(v.y, tp[4], a4); tp += KD;
        a0 = fmaf(v.z, tp[0], a0); a1 = fmaf(v.z, tp[1], a1); a2 = fmaf(v.z, tp[2], a2);
        a3 = fmaf(v.z, tp[3], a3); a4 = fmaf(v.z, tp[4], a4); tp += KD;
        a0 = fmaf(v.w, tp[0], a0); a1 = fmaf(v.w, tp[1], a1); a2 = fmaf(v.w, tp[2], a2);
        a3 = fmaf(v.w, tp[3], a3); a4 = fmaf(v.w, tp[4], a4);
    }
    xk[t][0] = a0; xk[t][1] = a1; xk[t][2] = a2; xk[t][3] = a3; xk[t][4] = a4;
    __syncthreads();
    if (t < BB) {
        xk[t][0] += xk[t + BB][0]; xk[t][1] += xk[t + BB][1]; xk[t][2] += xk[t + BB][2];
        xk[t][3] += xk[t + BB][3]; xk[t][4] += xk[t + BB][4];
    }
    __syncthreads();

    const int jg = t >> 9;
    const float4 xiv = *(const float4*)&xk[i][0];
    const float xi4 = xk[i][4];
    float s0 = 0.f;
    const int j0 = jg << 8;
    for (int jj = 0; jj < 256; ++jj) {
        const int j = j0 + jj;
        float4 xj = *(const float4*)&xk[j][0];
        float xj4 = xk[j][4];
        float aa = (fabsf(xiv.x - xj.x) + fabsf(xiv.y - xj.y))
                 + (fabsf(xiv.z - xj.z) + fabsf(xiv.w - xj.w)) + fabsf(xi4 - xj4);
        s0 += __builtin_amdgcn_exp2f(-1.4426950408889634f * aa);
    }
    xk[BB + i][jg] = s0;
    __syncthreads();
    if (t < BB)
        out[(size_t)t * KK + k] = xk[BB + t][0] + xk[BB + t][1];
}

// ---------------- launch ----------------
extern "C" void kernel_launch(void* const* d_in, const int* in_sizes, int n_in,
                              void* d_out, int out_size, void* d_ws, size_t ws_size,
                              hipStream_t stream) {
    const float* in = (const float*)d_in[0];   // [512, 1024]
    const float* T  = (const float*)d_in[1];   // [1024, 500]
    float* out = (float*)d_out;                // [512, 100]

    const size_t xpT_bytes = (size_t)SPLITS * KDP * BB * sizeof(float);  // 8 MiB
    const size_t xT_bytes  = (size_t)KDP * BB * sizeof(float);           // 1 MiB

    if (ws_size < xpT_bytes + xT_bytes) {
        mbd_fused<<<KK, 1024, 0, stream>>>(in, T, out);
        return;
    }

    float* xpT = (float*)d_ws;
    float* xT  = (float*)((char*)d_ws + xpT_bytes);

    kA<<<512, 256, 0, stream>>>(in, T, xpT);
    kB<<<256, 256, 0, stream>>>(xpT, xT);

    dim3 g3(KK, 2);                    // 200 blocks x 1024 threads
    pairW<<<g3, 1024, 0, stream>>>(xT, out);
}